// Round 1
// baseline (1067.067 us; speedup 1.0000x reference)
//
#include <hip/hip_runtime.h>

#define N_ROWS 4096
#define D_DIM  2048
#define V_DIM  32000

typedef unsigned short u16;
typedef __attribute__((ext_vector_type(8))) short bf16x8;
typedef __attribute__((ext_vector_type(4))) float f32x4;

__device__ __forceinline__ u16 f2bf(float f) {
    unsigned int u = __float_as_uint(f);
    u += 0x7FFFu + ((u >> 16) & 1u);   // RNE
    return (u16)(u >> 16);
}

// ---- zero the per-row accumulators (ws is poisoned 0xAA before every call) ----
__global__ void init_acc(float* __restrict__ p, int n) {
    int i = blockIdx.x * blockDim.x + threadIdx.x;
    if (i < n) p[i] = 0.0f;
}

// ---- convert input A fp32 [N,D] -> bf16 [N,D] ----
__global__ void convert_a(const float4* __restrict__ in, ushort4* __restrict__ out, int n4) {
    int i = blockIdx.x * blockDim.x + threadIdx.x;
    int stride = gridDim.x * blockDim.x;
    for (; i < n4; i += stride) {
        float4 v = in[i];
        ushort4 o;
        o.x = f2bf(v.x); o.y = f2bf(v.y); o.z = f2bf(v.z); o.w = f2bf(v.w);
        out[i] = o;
    }
}

// ---- transpose-convert weight fp32 [D,V] -> bf16 Wt [V,D] (K-contiguous for MFMA B-frags) ----
__global__ void transpose_w(const float* __restrict__ W, u16* __restrict__ Wt) {
    __shared__ float tile[64][65];           // +1 pad: conflict-free transposed reads
    int v0 = blockIdx.x * 64;
    int d0 = blockIdx.y * 64;
    int tc = threadIdx.x & 63;
    int tr = threadIdx.x >> 6;               // 0..3 (wave id)
#pragma unroll
    for (int i = 0; i < 16; ++i) {
        int r = tr * 16 + i;
        tile[r][tc] = W[(size_t)(d0 + r) * V_DIM + v0 + tc];   // coalesced along V
    }
    __syncthreads();
#pragma unroll
    for (int i = 0; i < 16; ++i) {
        int r = tr * 16 + i;
        Wt[(size_t)(v0 + r) * D_DIM + d0 + tc] = f2bf(tile[tc][r]);  // coalesced along D
    }
}

// ---- fused GEMM + softcap + partial CE reductions ----
// C-tile 128x128, BK=32, 4 waves (2x2), each wave 4x4 grid of 16x16x32 bf16 MFMAs.
// A[N,D] bf16 row-major (K-contig), Wt[V,D] bf16 row-major (K-contig).
// Epilogue: l = 30*tanh(acc/30); atomically accumulate per-row sum(e^l), sum(l);
// store l at the target column (unique writer per row).
__global__ __launch_bounds__(256) void gemm_ce(
    const u16* __restrict__ A, const u16* __restrict__ Wt,
    const int* __restrict__ targets,
    float* __restrict__ sumexp, float* __restrict__ sumlog, float* __restrict__ tlogit)
{
    __shared__ u16 lsA[128 * 32];
    __shared__ u16 lsB[128 * 32];

    const int tid   = threadIdx.x;
    const int lane  = tid & 63;
    const int wave  = tid >> 6;
    const int wr    = wave >> 1, wc = wave & 1;
    const int col16 = lane & 15, quad = lane >> 4;

    const int rowbase = blockIdx.x * 128;
    const int colbase = blockIdx.y * 128;

    f32x4 acc[4][4];
#pragma unroll
    for (int i = 0; i < 4; ++i)
#pragma unroll
        for (int j = 0; j < 4; ++j)
            acc[i][j] = (f32x4){0.f, 0.f, 0.f, 0.f};

    // staging chunks: chunk c covers row c>>2, k-span (c&3)*8..+8 (16B). c = tid and tid+256.
    const int c0 = tid, c1 = tid + 256;
    const u16* gA0 = A  + (size_t)(rowbase + (c0 >> 2)) * D_DIM + (c0 & 3) * 8;
    const u16* gA1 = A  + (size_t)(rowbase + (c1 >> 2)) * D_DIM + (c1 & 3) * 8;
    const u16* gB0 = Wt + (size_t)(colbase + (c0 >> 2)) * D_DIM + (c0 & 3) * 8;
    const u16* gB1 = Wt + (size_t)(colbase + (c1 >> 2)) * D_DIM + (c1 & 3) * 8;
    u16* lA0 = &lsA[c0 * 8];
    u16* lA1 = &lsA[c1 * 8];
    u16* lB0 = &lsB[c0 * 8];
    u16* lB1 = &lsB[c1 * 8];

    for (int kt = 0; kt < D_DIM / 32; ++kt) {
        const int ko = kt * 32;
        __builtin_amdgcn_global_load_lds(
            (const __attribute__((address_space(1))) void*)(gA0 + ko),
            (__attribute__((address_space(3))) void*)lA0, 16, 0, 0);
        __builtin_amdgcn_global_load_lds(
            (const __attribute__((address_space(1))) void*)(gA1 + ko),
            (__attribute__((address_space(3))) void*)lA1, 16, 0, 0);
        __builtin_amdgcn_global_load_lds(
            (const __attribute__((address_space(1))) void*)(gB0 + ko),
            (__attribute__((address_space(3))) void*)lB0, 16, 0, 0);
        __builtin_amdgcn_global_load_lds(
            (const __attribute__((address_space(1))) void*)(gB1 + ko),
            (__attribute__((address_space(3))) void*)lB1, 16, 0, 0);
        __syncthreads();

        bf16x8 af[4], bfr[4];
#pragma unroll
        for (int mi = 0; mi < 4; ++mi)
            af[mi] = *(const bf16x8*)&lsA[(wr * 64 + mi * 16 + col16) * 32 + quad * 8];
#pragma unroll
        for (int ni = 0; ni < 4; ++ni)
            bfr[ni] = *(const bf16x8*)&lsB[(wc * 64 + ni * 16 + col16) * 32 + quad * 8];

#pragma unroll
        for (int mi = 0; mi < 4; ++mi)
#pragma unroll
            for (int ni = 0; ni < 4; ++ni)
                acc[mi][ni] = __builtin_amdgcn_mfma_f32_16x16x32_bf16(
                    af[mi], bfr[ni], acc[mi][ni], 0, 0, 0);
        __syncthreads();
    }

    // ---- epilogue: C/D layout col=lane&15, row=quad*4+reg (m89-verified) ----
#pragma unroll
    for (int mi = 0; mi < 4; ++mi) {
        int grows[4], tgts[4];
#pragma unroll
        for (int r = 0; r < 4; ++r) {
            grows[r] = rowbase + wr * 64 + mi * 16 + quad * 4 + r;
            tgts[r]  = targets[grows[r]];
        }
        float se[4] = {0.f, 0.f, 0.f, 0.f};
        float sl[4] = {0.f, 0.f, 0.f, 0.f};
#pragma unroll
        for (int ni = 0; ni < 4; ++ni) {
            int gcol = colbase + wc * 64 + ni * 16 + col16;
            f32x4 v = acc[mi][ni];
#pragma unroll
            for (int r = 0; r < 4; ++r) {
                float a  = v[r];
                float e2 = __expf(a * (2.0f / 30.0f));     // exp(2*a/30)
                float th = 1.0f - 2.0f / (e2 + 1.0f);      // tanh(a/30), saturates cleanly
                float l  = 30.0f * th;
                float el = __expf(l);
                se[r] += el;
                sl[r] += l;
                if (tgts[r] == gcol) tlogit[grows[r]] = l; // unique writer
            }
        }
#pragma unroll
        for (int r = 0; r < 4; ++r) {
            float e = se[r], s = sl[r];
#pragma unroll
            for (int off = 1; off < 16; off <<= 1) {
                e += __shfl_xor(e, off);
                s += __shfl_xor(s, off);
            }
            if (col16 == 0) {
                atomicAdd(&sumexp[grows[r]], e);
                atomicAdd(&sumlog[grows[r]], s);
            }
        }
    }
}

// ---- final scalar reduction ----
__global__ void finalize(const float* __restrict__ sumexp, const float* __restrict__ sumlog,
                         const float* __restrict__ tlogit, const int* __restrict__ targets,
                         float* __restrict__ out)
{
    const int tid = threadIdx.x;
    float acc = 0.f, cnt = 0.f;
    for (int r = tid; r < N_ROWS; r += 256) {
        int tg = targets[r];
        if (tg != -100) {
            float lse    = __logf(sumexp[r]);
            float nll    = lse - tlogit[r];
            float smooth = lse - sumlog[r] * (1.0f / V_DIM);
            float ce     = 0.9f * nll + 0.1f * smooth;
            float z      = 1e-4f * lse * lse;
            acc += ce + z;
            cnt += 1.f;
        }
    }
#pragma unroll
    for (int off = 1; off < 64; off <<= 1) {
        acc += __shfl_xor(acc, off);
        cnt += __shfl_xor(cnt, off);
    }
    __shared__ float sa[4], sc[4];
    if ((tid & 63) == 0) { sa[tid >> 6] = acc; sc[tid >> 6] = cnt; }
    __syncthreads();
    if (tid == 0) {
        float t = sa[0] + sa[1] + sa[2] + sa[3];
        float c = sc[0] + sc[1] + sc[2] + sc[3];
        out[0] = t / c;
    }
}

extern "C" void kernel_launch(void* const* d_in, const int* in_sizes, int n_in,
                              void* d_out, int out_size, void* d_ws, size_t ws_size,
                              hipStream_t stream) {
    const float* A  = (const float*)d_in[0];   // [4096, 2048]
    const float* W  = (const float*)d_in[1];   // [2048, 32000]
    const int*   tg = (const int*)d_in[2];     // [4096]
    // d_in[3] = bias scalar 0 (falsy) -> ignored
    float* out = (float*)d_out;

    char* ws = (char*)d_ws;
    u16* Abf = (u16*)ws;
    size_t off = (size_t)N_ROWS * D_DIM * sizeof(u16);      // 16 MB
    u16* Wt = (u16*)(ws + off);
    off += (size_t)V_DIM * D_DIM * sizeof(u16);             // 128 MB
    float* sumexp = (float*)(ws + off); off += (size_t)N_ROWS * sizeof(float);
    float* sumlog = (float*)(ws + off); off += (size_t)N_ROWS * sizeof(float);
    float* tlog   = (float*)(ws + off); off += (size_t)N_ROWS * sizeof(float);

    // sumexp/sumlog/tlog are contiguous: one zeroing pass
    init_acc<<<dim3((N_ROWS * 3 + 255) / 256), 256, 0, stream>>>(sumexp, N_ROWS * 3);
    convert_a<<<dim3(512), 256, 0, stream>>>((const float4*)A, (ushort4*)Abf,
                                             N_ROWS * D_DIM / 4);
    transpose_w<<<dim3(V_DIM / 64, D_DIM / 64), 256, 0, stream>>>(W, Wt);
    gemm_ce<<<dim3(N_ROWS / 128, V_DIM / 128), 256, 0, stream>>>(Abf, Wt, tg,
                                                                 sumexp, sumlog, tlog);
    finalize<<<1, 256, 0, stream>>>(sumexp, sumlog, tlog, tg, out);
}

// Round 2
// 1048.869 us; speedup vs baseline: 1.0174x; 1.0174x over previous
//
#include <hip/hip_runtime.h>

#define N_ROWS 4096
#define D_DIM  2048
#define V_DIM  32000

typedef unsigned short u16;
typedef __attribute__((ext_vector_type(8))) short bf16x8;
typedef __attribute__((ext_vector_type(8))) u16 u16x8;
typedef __attribute__((ext_vector_type(4))) float f32x4;

__device__ __forceinline__ u16 f2bf(float f) {
    unsigned int u = __float_as_uint(f);
    u += 0x7FFFu + ((u >> 16) & 1u);   // RNE
    return (u16)(u >> 16);
}

// ---- zero the per-row accumulators (ws is poisoned 0xAA before every call) ----
__global__ void init_acc(float* __restrict__ p, int n) {
    int i = blockIdx.x * blockDim.x + threadIdx.x;
    if (i < n) p[i] = 0.0f;
}

// ---- convert input A fp32 [N,D] -> bf16 [N,D] ----
__global__ void convert_a(const float4* __restrict__ in, ushort4* __restrict__ out, int n4) {
    int i = blockIdx.x * blockDim.x + threadIdx.x;
    int stride = gridDim.x * blockDim.x;
    for (; i < n4; i += stride) {
        float4 v = in[i];
        ushort4 o;
        o.x = f2bf(v.x); o.y = f2bf(v.y); o.z = f2bf(v.z); o.w = f2bf(v.w);
        out[i] = o;
    }
}

// ---- transpose-convert weight fp32 [D,V] -> bf16 Wt [V,D] ----
// 64x64 tile; float4 (16B/lane) loads, 16B/lane transposed stores.
__global__ __launch_bounds__(256) void transpose_w(const float* __restrict__ W,
                                                   u16* __restrict__ Wt) {
    __shared__ u16 tile[64][72];             // 72 u16 = 144 B row stride (16B-aligned)
    const int v0 = blockIdx.x * 64;
    const int d0 = blockIdx.y * 64;
    const int tid = threadIdx.x;

    // load: thread covers 4 d-rows x 4 v (float4). vchunk = tid&15, drow = tid>>4.
    const int vch = (tid & 15) * 4;
    const int dr0 = tid >> 4;                // 0..15
#pragma unroll
    for (int i = 0; i < 4; ++i) {
        int d = dr0 + i * 16;
        float4 w = *(const float4*)&W[(size_t)(d0 + d) * V_DIM + v0 + vch];
        tile[vch + 0][d] = f2bf(w.x);
        tile[vch + 1][d] = f2bf(w.y);
        tile[vch + 2][d] = f2bf(w.z);
        tile[vch + 3][d] = f2bf(w.w);
    }
    __syncthreads();

    // store: thread writes 2 x 16B chunks along D. chunk = v*8 + d8.
#pragma unroll
    for (int i = 0; i < 2; ++i) {
        int chunk = tid + i * 256;           // 0..511
        int v  = chunk >> 3;
        int d8 = (chunk & 7) * 8;
        u16x8 val = *(const u16x8*)&tile[v][d8];
        *(u16x8*)&Wt[(size_t)(v0 + v) * D_DIM + d0 + d8] = val;
    }
}

// ---- fused GEMM + softcap + partial CE reductions ----
// C-tile 128x128, BK=32, 4 waves (2x2), each wave 4x4 grid of 16x16x32 bf16 MFMAs.
// LDS chunk swizzle: 16B chunk k8 of row r lives at slot k8 ^ ((r>>1)&3) --
// spreads ds_read_b128 frag reads across all 8 bank groups (2-way = free).
__global__ __launch_bounds__(256) void gemm_ce(
    const u16* __restrict__ A, const u16* __restrict__ Wt,
    const int* __restrict__ targets,
    float* __restrict__ sumexp, float* __restrict__ sumlog, float* __restrict__ tlogit)
{
    __shared__ u16 lsA[128 * 32];
    __shared__ u16 lsB[128 * 32];

    const int tid   = threadIdx.x;
    const int lane  = tid & 63;
    const int wave  = tid >> 6;
    const int wr    = wave >> 1, wc = wave & 1;
    const int col16 = lane & 15, quad = lane >> 4;

    const int rowbase = blockIdx.x * 128;
    const int colbase = blockIdx.y * 128;

    f32x4 acc[4][4];
#pragma unroll
    for (int i = 0; i < 4; ++i)
#pragma unroll
        for (int j = 0; j < 4; ++j)
            acc[i][j] = (f32x4){0.f, 0.f, 0.f, 0.f};

    // staging chunk c -> LDS bytes [c*16, c*16+16); fetches global k8 = (c&3)^((c>>3)&3)
    const int c0 = tid, c1 = tid + 256;
    const int k80 = ((c0 & 3) ^ ((c0 >> 3) & 3)) * 8;
    const int k81 = ((c1 & 3) ^ ((c1 >> 3) & 3)) * 8;
    const u16* gA0 = A  + (size_t)(rowbase + (c0 >> 2)) * D_DIM + k80;
    const u16* gA1 = A  + (size_t)(rowbase + (c1 >> 2)) * D_DIM + k81;
    const u16* gB0 = Wt + (size_t)(colbase + (c0 >> 2)) * D_DIM + k80;
    const u16* gB1 = Wt + (size_t)(colbase + (c1 >> 2)) * D_DIM + k81;
    u16* lA0 = &lsA[c0 * 8];
    u16* lA1 = &lsA[c1 * 8];
    u16* lB0 = &lsB[c0 * 8];
    u16* lB1 = &lsB[c1 * 8];

    // frag-read swizzled chunk offsets (inverse xor), in u16 elements
    const int arow[4] = { wr * 64 +  0 + col16, wr * 64 + 16 + col16,
                          wr * 64 + 32 + col16, wr * 64 + 48 + col16 };
    const int brow[4] = { wc * 64 +  0 + col16, wc * 64 + 16 + col16,
                          wc * 64 + 32 + col16, wc * 64 + 48 + col16 };
    int aoff[4], boff[4];
#pragma unroll
    for (int i = 0; i < 4; ++i) {
        aoff[i] = arow[i] * 32 + (quad ^ ((arow[i] >> 1) & 3)) * 8;
        boff[i] = brow[i] * 32 + (quad ^ ((brow[i] >> 1) & 3)) * 8;
    }

    for (int kt = 0; kt < D_DIM / 32; ++kt) {
        const int ko = kt * 32;
        __builtin_amdgcn_global_load_lds(
            (const __attribute__((address_space(1))) void*)(gA0 + ko),
            (__attribute__((address_space(3))) void*)lA0, 16, 0, 0);
        __builtin_amdgcn_global_load_lds(
            (const __attribute__((address_space(1))) void*)(gA1 + ko),
            (__attribute__((address_space(3))) void*)lA1, 16, 0, 0);
        __builtin_amdgcn_global_load_lds(
            (const __attribute__((address_space(1))) void*)(gB0 + ko),
            (__attribute__((address_space(3))) void*)lB0, 16, 0, 0);
        __builtin_amdgcn_global_load_lds(
            (const __attribute__((address_space(1))) void*)(gB1 + ko),
            (__attribute__((address_space(3))) void*)lB1, 16, 0, 0);
        __syncthreads();

        bf16x8 af[4], bfr[4];
#pragma unroll
        for (int mi = 0; mi < 4; ++mi) af[mi]  = *(const bf16x8*)&lsA[aoff[mi]];
#pragma unroll
        for (int ni = 0; ni < 4; ++ni) bfr[ni] = *(const bf16x8*)&lsB[boff[ni]];

#pragma unroll
        for (int mi = 0; mi < 4; ++mi)
#pragma unroll
            for (int ni = 0; ni < 4; ++ni)
                acc[mi][ni] = __builtin_amdgcn_mfma_f32_16x16x32_bf16(
                    af[mi], bfr[ni], acc[mi][ni], 0, 0, 0);
        __syncthreads();
    }

    // ---- epilogue: C/D layout col=lane&15, row=quad*4+reg (m89-verified) ----
#pragma unroll
    for (int mi = 0; mi < 4; ++mi) {
        int grows[4], tgts[4];
#pragma unroll
        for (int r = 0; r < 4; ++r) {
            grows[r] = rowbase + wr * 64 + mi * 16 + quad * 4 + r;
            tgts[r]  = targets[grows[r]];
        }
        float se[4] = {0.f, 0.f, 0.f, 0.f};
        float sl[4] = {0.f, 0.f, 0.f, 0.f};
#pragma unroll
        for (int ni = 0; ni < 4; ++ni) {
            int gcol = colbase + wc * 64 + ni * 16 + col16;
            f32x4 v = acc[mi][ni];
#pragma unroll
            for (int r = 0; r < 4; ++r) {
                float a  = v[r];
                float e2 = __expf(a * (2.0f / 30.0f));     // exp(2*a/30)
                float th = 1.0f - 2.0f / (e2 + 1.0f);      // tanh(a/30)
                float l  = 30.0f * th;
                float el = __expf(l);
                se[r] += el;
                sl[r] += l;
                if (tgts[r] == gcol) tlogit[grows[r]] = l; // unique writer
            }
        }
#pragma unroll
        for (int r = 0; r < 4; ++r) {
            float e = se[r], s = sl[r];
#pragma unroll
            for (int off = 1; off < 16; off <<= 1) {
                e += __shfl_xor(e, off);
                s += __shfl_xor(s, off);
            }
            if (col16 == 0) {
                atomicAdd(&sumexp[grows[r]], e);
                atomicAdd(&sumlog[grows[r]], s);
            }
        }
    }
}

// ---- final scalar reduction ----
__global__ void finalize(const float* __restrict__ sumexp, const float* __restrict__ sumlog,
                         const float* __restrict__ tlogit, const int* __restrict__ targets,
                         float* __restrict__ out)
{
    const int tid = threadIdx.x;
    float acc = 0.f, cnt = 0.f;
    for (int r = tid; r < N_ROWS; r += 256) {
        int tg = targets[r];
        if (tg != -100) {
            float lse    = __logf(sumexp[r]);
            float nll    = lse - tlogit[r];
            float smooth = lse - sumlog[r] * (1.0f / V_DIM);
            float ce     = 0.9f * nll + 0.1f * smooth;
            float z      = 1e-4f * lse * lse;
            acc += ce + z;
            cnt += 1.f;
        }
    }
#pragma unroll
    for (int off = 1; off < 64; off <<= 1) {
        acc += __shfl_xor(acc, off);
        cnt += __shfl_xor(cnt, off);
    }
    __shared__ float sa[4], sc[4];
    if ((tid & 63) == 0) { sa[tid >> 6] = acc; sc[tid >> 6] = cnt; }
    __syncthreads();
    if (tid == 0) {
        float t = sa[0] + sa[1] + sa[2] + sa[3];
        float c = sc[0] + sc[1] + sc[2] + sc[3];
        out[0] = t / c;
    }
}

extern "C" void kernel_launch(void* const* d_in, const int* in_sizes, int n_in,
                              void* d_out, int out_size, void* d_ws, size_t ws_size,
                              hipStream_t stream) {
    const float* A  = (const float*)d_in[0];   // [4096, 2048]
    const float* W  = (const float*)d_in[1];   // [2048, 32000]
    const int*   tg = (const int*)d_in[2];     // [4096]
    // d_in[3] = bias scalar 0 (falsy) -> ignored
    float* out = (float*)d_out;

    char* ws = (char*)d_ws;
    u16* Abf = (u16*)ws;
    size_t off = (size_t)N_ROWS * D_DIM * sizeof(u16);      // 16 MB
    u16* Wt = (u16*)(ws + off);
    off += (size_t)V_DIM * D_DIM * sizeof(u16);             // 128 MB
    float* sumexp = (float*)(ws + off); off += (size_t)N_ROWS * sizeof(float);
    float* sumlog = (float*)(ws + off); off += (size_t)N_ROWS * sizeof(float);
    float* tlog   = (float*)(ws + off); off += (size_t)N_ROWS * sizeof(float);

    // sumexp/sumlog/tlog are contiguous: one zeroing pass
    init_acc<<<dim3((N_ROWS * 3 + 255) / 256), 256, 0, stream>>>(sumexp, N_ROWS * 3);
    convert_a<<<dim3(512), 256, 0, stream>>>((const float4*)A, (ushort4*)Abf,
                                             N_ROWS * D_DIM / 4);
    transpose_w<<<dim3(V_DIM / 64, D_DIM / 64), 256, 0, stream>>>(W, Wt);
    gemm_ce<<<dim3(N_ROWS / 128, V_DIM / 128), 256, 0, stream>>>(Abf, Wt, tg,
                                                                 sumexp, sumlog, tlog);
    finalize<<<1, 256, 0, stream>>>(sumexp, sumlog, tlog, tg, out);
}